// Round 1
// baseline (1124.382 us; speedup 1.0000x reference)
//
#include <hip/hip_runtime.h>
#include <cstdint>

#define NROWS 2048
#define DDIM  1024
#define NCLS  128000
#define BM 128
#define BN 128
#define BK 32
#define RTILES (NROWS / BM)   // 16
#define CTILES (NCLS / BN)    // 1000

typedef __attribute__((ext_vector_type(8))) short bf16x8;
typedef __attribute__((ext_vector_type(4))) float f32x4;

__device__ __forceinline__ unsigned short f2bf(float x) {
    unsigned int u = __float_as_uint(x);
    u += 0x7fffu + ((u >> 16) & 1u);   // round-to-nearest-even
    return (unsigned short)(u >> 16);
}

__device__ __forceinline__ uint4 pack8(float4 a, float4 b) {
    uint4 r;
    r.x = (unsigned)f2bf(a.x) | ((unsigned)f2bf(a.y) << 16);
    r.y = (unsigned)f2bf(a.z) | ((unsigned)f2bf(a.w) << 16);
    r.z = (unsigned)f2bf(b.x) | ((unsigned)f2bf(b.y) << 16);
    r.w = (unsigned)f2bf(b.z) | ((unsigned)f2bf(b.w) << 16);
    return r;
}

__device__ __forceinline__ void async_load16(unsigned short* lds, const unsigned short* g) {
    __builtin_amdgcn_global_load_lds(
        (const __attribute__((address_space(1))) unsigned int*)(uintptr_t)g,
        (__attribute__((address_space(3))) unsigned int*)(uintptr_t)lds,
        16, 0, 0);
}

// features f32 -> bf16, pre-swizzled: within each 32-elem k-block, logical
// 8-elem slot s stored at phys slot s ^ ((row>>1)&3)  (T2 via m173 pattern)
__global__ void convert_features(const float* __restrict__ f, unsigned short* __restrict__ out) {
    int idx = blockIdx.x * 256 + threadIdx.x;  // one per 8-elem slot
    int row = idx >> 7;
    int sl  = idx & 127;
    int kb  = sl >> 2;
    int s   = sl & 3;
    const float* src = f + (size_t)row * DDIM + kb * 32 + s * 8;
    float4 v0 = *(const float4*)(src);
    float4 v1 = *(const float4*)(src + 4);
    int ps = s ^ ((row >> 1) & 3);
    *(uint4*)(out + (size_t)row * DDIM + kb * 32 + ps * 8) = pack8(v0, v1);
}

__global__ __launch_bounds__(256) void gemm_loss(
    const unsigned short* __restrict__ fbf,
    const float* __restrict__ weight,
    const float* __restrict__ bias,
    const long long* __restrict__ target,
    float* __restrict__ partials,   // [NROWS][CTILES]
    float* __restrict__ tlogit)     // [NROWS]
{
    __shared__ __align__(16) unsigned short Atile[BM * BK];
    __shared__ __align__(16) unsigned short Btile[BN * BK];
    __shared__ float rowsum2[BM][2];

    // XCD-bijective swizzle (nwg=16000, %8==0); row-tile fastest so the 16
    // blocks sharing one weight panel are consecutive within an XCD chunk.
    const int cpx = (RTILES * CTILES) / 8;
    int wg  = blockIdx.x;
    int swz = (wg & 7) * cpx + (wg >> 3);
    const int rt = swz & (RTILES - 1);
    const int ct = swz >> 4;
    const int brow = rt * BM;
    const int bcol = ct * BN;

    const int tid  = threadIdx.x;
    const int lane = tid & 63;
    const int wid  = tid >> 6;
    const int wr = wid >> 1;
    const int wc = wid & 1;

    // A staging via global_load_lds: wave wid fills LDS chunks (wid*2+i)*1024B
    const int ar0  = (wid * 2 + 0) * 16 + (lane >> 2);
    const int ar1  = (wid * 2 + 1) * 16 + (lane >> 2);
    const int acol = (lane & 3) * 8;  // ushort units (16B chunk)
    const unsigned short* ga0 = fbf + (size_t)(brow + ar0) * DDIM + acol;
    const unsigned short* ga1 = fbf + (size_t)(brow + ar1) * DDIM + acol;
    unsigned short* la0 = &Atile[(wid * 2 + 0) * 512];
    unsigned short* la1 = &Atile[(wid * 2 + 1) * 512];

    // B staging: thread handles 16 f32 of one class-row, converts, swizzled write
    const int bro = tid >> 1;
    const int bha = tid & 1;
    const float* gb = weight + (size_t)(bcol + bro) * DDIM + bha * 16;
    const int bswz = (bro >> 1) & 3;
    unsigned short* lb0 = &Btile[bro * 32 + (((bha * 2 + 0) ^ bswz) * 8)];
    unsigned short* lb1 = &Btile[bro * 32 + (((bha * 2 + 1) ^ bswz) * 8)];

    // fragment read offsets (swizzled)
    const int fr = lane & 15;
    const int gk = lane >> 4;
    int aoff[4], boff[4];
#pragma unroll
    for (int m = 0; m < 4; ++m) {
        int r = wr * 64 + m * 16 + fr;
        aoff[m] = r * 32 + ((gk ^ ((r >> 1) & 3)) * 8);
    }
#pragma unroll
    for (int n = 0; n < 4; ++n) {
        int c = wc * 64 + n * 16 + fr;
        boff[n] = c * 32 + ((gk ^ ((c >> 1) & 3)) * 8);
    }

    f32x4 acc[4][4] = {};

    for (int kk = 0; kk < DDIM; kk += BK) {
        // B global loads (f32)
        const float4* pb = (const float4*)(gb + kk);
        float4 v0 = pb[0], v1 = pb[1], v2 = pb[2], v3 = pb[3];
        // A direct-to-LDS
        async_load16(la0, ga0 + kk);
        async_load16(la1, ga1 + kk);
        // B convert + swizzled LDS write
        *(uint4*)lb0 = pack8(v0, v1);
        *(uint4*)lb1 = pack8(v2, v3);
        __syncthreads();   // drains vmcnt (gll) + lgkmcnt (ds_write)

        bf16x8 af[4], bfr[4];
#pragma unroll
        for (int m = 0; m < 4; ++m) af[m]  = *(const bf16x8*)&Atile[aoff[m]];
#pragma unroll
        for (int n = 0; n < 4; ++n) bfr[n] = *(const bf16x8*)&Btile[boff[n]];
#pragma unroll
        for (int m = 0; m < 4; ++m)
#pragma unroll
            for (int n = 0; n < 4; ++n)
                acc[m][n] = __builtin_amdgcn_mfma_f32_16x16x32_bf16(af[m], bfr[n], acc[m][n], 0, 0, 0);
        __syncthreads();   // protect LDS before next stage
    }

    // ---- epilogue: bias, exp-sum over this block's 128 classes, target gather
    float bval[4];
    int cls[4];
#pragma unroll
    for (int n = 0; n < 4; ++n) {
        cls[n]  = bcol + wc * 64 + n * 16 + fr;
        bval[n] = bias[cls[n]];
    }
#pragma unroll
    for (int m = 0; m < 4; ++m) {
#pragma unroll
        for (int j = 0; j < 4; ++j) {
            int rloc = wr * 64 + m * 16 + gk * 4 + j;   // C/D row = (lane>>4)*4 + reg
            long long tgt = target[brow + rloc];
            float s = 0.f;
#pragma unroll
            for (int n = 0; n < 4; ++n) {
                float lg = acc[m][n][j] + bval[n];
                if (tgt == (long long)cls[n]) tlogit[brow + rloc] = lg;
                s += __expf(lg);
            }
#pragma unroll
            for (int off = 1; off < 16; off <<= 1) s += __shfl_xor(s, off, 64);
            if (fr == 0) rowsum2[rloc][wc] = s;
        }
    }
    __syncthreads();
    if (tid < BM) {
        partials[(size_t)(brow + tid) * CTILES + ct] = rowsum2[tid][0] + rowsum2[tid][1];
    }
}

__global__ void row_reduce(const float* __restrict__ partials,
                           const float* __restrict__ tlogit,
                           float* __restrict__ rowloss) {
    int lane = threadIdx.x & 63;
    int wid  = threadIdx.x >> 6;
    int row  = blockIdx.x * 4 + wid;
    const float* p = partials + (size_t)row * CTILES;
    float s = 0.f;
    for (int i = lane; i < CTILES; i += 64) s += p[i];
#pragma unroll
    for (int off = 1; off < 64; off <<= 1) s += __shfl_xor(s, off, 64);
    if (lane == 0) rowloss[row] = __logf(s) - tlogit[row];
}

__global__ void final_reduce(const float* __restrict__ rowloss, float* __restrict__ out) {
    __shared__ float red[256];
    int tid = threadIdx.x;
    float s = 0.f;
    for (int i = tid; i < NROWS; i += 256) s += rowloss[i];
    red[tid] = s;
    __syncthreads();
    for (int off = 128; off > 0; off >>= 1) {
        if (tid < off) red[tid] += red[tid + off];
        __syncthreads();
    }
    if (tid == 0) out[0] = red[0] * (1.0f / NROWS);
}

extern "C" void kernel_launch(void* const* d_in, const int* in_sizes, int n_in,
                              void* d_out, int out_size, void* d_ws, size_t ws_size,
                              hipStream_t stream) {
    const float*     features = (const float*)d_in[0];
    const long long* target   = (const long long*)d_in[1];
    const float*     weight   = (const float*)d_in[2];
    const float*     bias     = (const float*)d_in[3];
    float* out = (float*)d_out;

    char* ws = (char*)d_ws;
    size_t off = 0;
    unsigned short* fbf = (unsigned short*)(ws + off); off += (size_t)NROWS * DDIM * 2;       // 4 MB
    float* partials     = (float*)(ws + off);          off += (size_t)NROWS * CTILES * 4;     // 8 MB
    float* tlogit       = (float*)(ws + off);          off += (size_t)NROWS * 4;
    float* rowloss      = (float*)(ws + off);          off += (size_t)NROWS * 4;

    hipLaunchKernelGGL(convert_features, dim3(NROWS * (DDIM / 8) / 256), dim3(256), 0, stream,
                       features, fbf);
    hipLaunchKernelGGL(gemm_loss, dim3(RTILES * CTILES), dim3(256), 0, stream,
                       fbf, weight, bias, target, partials, tlogit);
    hipLaunchKernelGGL(row_reduce, dim3(NROWS / 4), dim3(256), 0, stream,
                       partials, tlogit, rowloss);
    hipLaunchKernelGGL(final_reduce, dim3(1), dim3(256), 0, stream,
                       rowloss, out);
}

// Round 2
// 899.868 us; speedup vs baseline: 1.2495x; 1.2495x over previous
//
#include <hip/hip_runtime.h>
#include <cstdint>

#define NROWS 2048
#define DDIM  1024
#define NCLS  128000
#define BM 128
#define BN 128
#define BK 32
#define RTILES (NROWS / BM)   // 16
#define CTILES (NCLS / BN)    // 1000

typedef __attribute__((ext_vector_type(8))) short bf16x8;
typedef __attribute__((ext_vector_type(4))) float f32x4;

__device__ __forceinline__ unsigned short f2bf(float x) {
    unsigned int u = __float_as_uint(x);
    u += 0x7fffu + ((u >> 16) & 1u);   // round-to-nearest-even
    return (unsigned short)(u >> 16);
}

__device__ __forceinline__ uint4 pack8(float4 a, float4 b) {
    uint4 r;
    r.x = (unsigned)f2bf(a.x) | ((unsigned)f2bf(a.y) << 16);
    r.y = (unsigned)f2bf(a.z) | ((unsigned)f2bf(a.w) << 16);
    r.z = (unsigned)f2bf(b.x) | ((unsigned)f2bf(b.y) << 16);
    r.w = (unsigned)f2bf(b.z) | ((unsigned)f2bf(b.w) << 16);
    return r;
}

__device__ __forceinline__ void async_load16(unsigned short* lds, const unsigned short* g) {
    __builtin_amdgcn_global_load_lds(
        (const __attribute__((address_space(1))) unsigned int*)(uintptr_t)g,
        (__attribute__((address_space(3))) unsigned int*)(uintptr_t)lds,
        16, 0, 0);
}

// f32 -> bf16 [rows][1024], pre-swizzled: within each 32-elem k-block,
// logical 8-elem slot s stored at phys slot s ^ ((row>>1)&3)  (m173 pattern)
__global__ void convert_swz(const float* __restrict__ src,
                            unsigned short* __restrict__ dst, long long nslots) {
    for (long long idx = blockIdx.x * 256LL + threadIdx.x; idx < nslots;
         idx += (long long)gridDim.x * 256) {
        long long row = idx >> 7;
        int sl = (int)(idx & 127);
        int kb = sl >> 2;
        int s  = sl & 3;
        const float* p = src + row * DDIM + kb * 32 + s * 8;
        float4 v0 = *(const float4*)p;
        float4 v1 = *(const float4*)(p + 4);
        int ps = s ^ (((int)row >> 1) & 3);
        *(uint4*)(dst + row * DDIM + kb * 32 + ps * 8) = pack8(v0, v1);
    }
}

// ---------------- main fused GEMM + partial softmax (bf16 A and B) ----------
__global__ __launch_bounds__(256) void gemm_bf16(
    const unsigned short* __restrict__ A,   // fbf, pre-swizzled [NROWS][DDIM]
    const unsigned short* __restrict__ B,   // wbf, pre-swizzled [NCLS][DDIM]
    const float* __restrict__ bias,
    const long long* __restrict__ target,
    float* __restrict__ partials,   // [NROWS][CTILES]
    float* __restrict__ tlogit)     // [NROWS]
{
    __shared__ __align__(16) unsigned short Atile[BM * BK];
    __shared__ __align__(16) unsigned short Btile[BN * BK];
    __shared__ float rowsum2[BM][2];

    // XCD-bijective swizzle (nwg=16000 % 8 == 0); row-tile fastest so the 16
    // blocks sharing one weight panel are consecutive within an XCD chunk.
    const int cpx = (RTILES * CTILES) / 8;
    int wg  = blockIdx.x;
    int swz = (wg & 7) * cpx + (wg >> 3);
    const int rt = swz & (RTILES - 1);
    const int ct = swz >> 4;
    const int brow = rt * BM;
    const int bcol = ct * BN;

    const int tid  = threadIdx.x;
    const int lane = tid & 63;
    const int wid  = tid >> 6;
    const int wr = wid >> 1;
    const int wc = wid & 1;

    // staging: wave wid fills LDS chunks; row/slot already swizzled on disk,
    // so source is read LINEARLY (phys slot order) and LDS stays linear.
    const int srow0 = (wid * 2 + 0) * 16 + (lane >> 2);
    const int srow1 = (wid * 2 + 1) * 16 + (lane >> 2);
    const int scol  = (lane & 3) * 8;   // phys slot * 8 (ushort units)
    const unsigned short* gA0 = A + (size_t)(brow + srow0) * DDIM + scol;
    const unsigned short* gA1 = A + (size_t)(brow + srow1) * DDIM + scol;
    const unsigned short* gB0 = B + (size_t)(bcol + srow0) * DDIM + scol;
    const unsigned short* gB1 = B + (size_t)(bcol + srow1) * DDIM + scol;
    unsigned short* lA0 = &Atile[(wid * 2 + 0) * 512];
    unsigned short* lA1 = &Atile[(wid * 2 + 1) * 512];
    unsigned short* lB0 = &Btile[(wid * 2 + 0) * 512];
    unsigned short* lB1 = &Btile[(wid * 2 + 1) * 512];

    // fragment read offsets (undo swizzle at read)
    const int fr = lane & 15;
    const int gk = lane >> 4;
    int aoff[4], boff[4];
#pragma unroll
    for (int m = 0; m < 4; ++m) {
        int r = wr * 64 + m * 16 + fr;
        aoff[m] = r * 32 + ((gk ^ ((r >> 1) & 3)) * 8);
    }
#pragma unroll
    for (int n = 0; n < 4; ++n) {
        int c = wc * 64 + n * 16 + fr;
        boff[n] = c * 32 + ((gk ^ ((c >> 1) & 3)) * 8);
    }

    f32x4 acc[4][4] = {};

    for (int kk = 0; kk < DDIM; kk += BK) {
        async_load16(lA0, gA0 + kk);
        async_load16(lA1, gA1 + kk);
        async_load16(lB0, gB0 + kk);
        async_load16(lB1, gB1 + kk);
        __syncthreads();   // drains vmcnt (global_load_lds)

        bf16x8 af[4], bfr[4];
#pragma unroll
        for (int m = 0; m < 4; ++m) af[m]  = *(const bf16x8*)&Atile[aoff[m]];
#pragma unroll
        for (int n = 0; n < 4; ++n) bfr[n] = *(const bf16x8*)&Btile[boff[n]];
#pragma unroll
        for (int m = 0; m < 4; ++m)
#pragma unroll
            for (int n = 0; n < 4; ++n)
                acc[m][n] = __builtin_amdgcn_mfma_f32_16x16x32_bf16(af[m], bfr[n], acc[m][n], 0, 0, 0);
        __syncthreads();   // protect LDS before next stage
    }

    // ---- epilogue: bias, exp-sum over this block's 128 classes, target gather
    float bval[4];
    int cls[4];
#pragma unroll
    for (int n = 0; n < 4; ++n) {
        cls[n]  = bcol + wc * 64 + n * 16 + fr;
        bval[n] = bias[cls[n]];
    }
#pragma unroll
    for (int m = 0; m < 4; ++m) {
#pragma unroll
        for (int j = 0; j < 4; ++j) {
            int rloc = wr * 64 + m * 16 + gk * 4 + j;   // C/D row = (lane>>4)*4 + reg
            long long tgt = target[brow + rloc];
            float s = 0.f;
#pragma unroll
            for (int n = 0; n < 4; ++n) {
                float lg = acc[m][n][j] + bval[n];
                if (tgt == (long long)cls[n]) tlogit[brow + rloc] = lg;
                s += __expf(lg);
            }
#pragma unroll
            for (int off = 1; off < 16; off <<= 1) s += __shfl_xor(s, off, 64);
            if (fr == 0) rowsum2[rloc][wc] = s;
        }
    }
    __syncthreads();
    if (tid < BM) {
        partials[(size_t)(brow + tid) * CTILES + ct] = rowsum2[tid][0] + rowsum2[tid][1];
    }
}

// ---------------- fallback (round-1 verified): in-loop f32 weight convert ---
__global__ __launch_bounds__(256) void gemm_f32w(
    const unsigned short* __restrict__ fbf,
    const float* __restrict__ weight,
    const float* __restrict__ bias,
    const long long* __restrict__ target,
    float* __restrict__ partials,
    float* __restrict__ tlogit)
{
    __shared__ __align__(16) unsigned short Atile[BM * BK];
    __shared__ __align__(16) unsigned short Btile[BN * BK];
    __shared__ float rowsum2[BM][2];

    const int cpx = (RTILES * CTILES) / 8;
    int wg  = blockIdx.x;
    int swz = (wg & 7) * cpx + (wg >> 3);
    const int rt = swz & (RTILES - 1);
    const int ct = swz >> 4;
    const int brow = rt * BM;
    const int bcol = ct * BN;

    const int tid  = threadIdx.x;
    const int lane = tid & 63;
    const int wid  = tid >> 6;
    const int wr = wid >> 1;
    const int wc = wid & 1;

    const int ar0  = (wid * 2 + 0) * 16 + (lane >> 2);
    const int ar1  = (wid * 2 + 1) * 16 + (lane >> 2);
    const int acol = (lane & 3) * 8;
    const unsigned short* ga0 = fbf + (size_t)(brow + ar0) * DDIM + acol;
    const unsigned short* ga1 = fbf + (size_t)(brow + ar1) * DDIM + acol;
    unsigned short* la0 = &Atile[(wid * 2 + 0) * 512];
    unsigned short* la1 = &Atile[(wid * 2 + 1) * 512];

    const int bro = tid >> 1;
    const int bha = tid & 1;
    const float* gb = weight + (size_t)(bcol + bro) * DDIM + bha * 16;
    const int bswz = (bro >> 1) & 3;
    unsigned short* lb0 = &Btile[bro * 32 + (((bha * 2 + 0) ^ bswz) * 8)];
    unsigned short* lb1 = &Btile[bro * 32 + (((bha * 2 + 1) ^ bswz) * 8)];

    const int fr = lane & 15;
    const int gk = lane >> 4;
    int aoff[4], boff[4];
#pragma unroll
    for (int m = 0; m < 4; ++m) {
        int r = wr * 64 + m * 16 + fr;
        aoff[m] = r * 32 + ((gk ^ ((r >> 1) & 3)) * 8);
    }
#pragma unroll
    for (int n = 0; n < 4; ++n) {
        int c = wc * 64 + n * 16 + fr;
        boff[n] = c * 32 + ((gk ^ ((c >> 1) & 3)) * 8);
    }

    f32x4 acc[4][4] = {};

    for (int kk = 0; kk < DDIM; kk += BK) {
        const float4* pb = (const float4*)(gb + kk);
        float4 v0 = pb[0], v1 = pb[1], v2 = pb[2], v3 = pb[3];
        async_load16(la0, ga0 + kk);
        async_load16(la1, ga1 + kk);
        *(uint4*)lb0 = pack8(v0, v1);
        *(uint4*)lb1 = pack8(v2, v3);
        __syncthreads();

        bf16x8 af[4], bfr[4];
#pragma unroll
        for (int m = 0; m < 4; ++m) af[m]  = *(const bf16x8*)&Atile[aoff[m]];
#pragma unroll
        for (int n = 0; n < 4; ++n) bfr[n] = *(const bf16x8*)&Btile[boff[n]];
#pragma unroll
        for (int m = 0; m < 4; ++m)
#pragma unroll
            for (int n = 0; n < 4; ++n)
                acc[m][n] = __builtin_amdgcn_mfma_f32_16x16x32_bf16(af[m], bfr[n], acc[m][n], 0, 0, 0);
        __syncthreads();
    }

    float bval[4];
    int cls[4];
#pragma unroll
    for (int n = 0; n < 4; ++n) {
        cls[n]  = bcol + wc * 64 + n * 16 + fr;
        bval[n] = bias[cls[n]];
    }
#pragma unroll
    for (int m = 0; m < 4; ++m) {
#pragma unroll
        for (int j = 0; j < 4; ++j) {
            int rloc = wr * 64 + m * 16 + gk * 4 + j;
            long long tgt = target[brow + rloc];
            float s = 0.f;
#pragma unroll
            for (int n = 0; n < 4; ++n) {
                float lg = acc[m][n][j] + bval[n];
                if (tgt == (long long)cls[n]) tlogit[brow + rloc] = lg;
                s += __expf(lg);
            }
#pragma unroll
            for (int off = 1; off < 16; off <<= 1) s += __shfl_xor(s, off, 64);
            if (fr == 0) rowsum2[rloc][wc] = s;
        }
    }
    __syncthreads();
    if (tid < BM) {
        partials[(size_t)(brow + tid) * CTILES + ct] = rowsum2[tid][0] + rowsum2[tid][1];
    }
}

__global__ void row_reduce(const float* __restrict__ partials,
                           const float* __restrict__ tlogit,
                           float* __restrict__ rowloss) {
    int lane = threadIdx.x & 63;
    int wid  = threadIdx.x >> 6;
    int row  = blockIdx.x * 4 + wid;
    const float* p = partials + (size_t)row * CTILES;
    float s = 0.f;
    for (int i = lane; i < CTILES; i += 64) s += p[i];
#pragma unroll
    for (int off = 1; off < 64; off <<= 1) s += __shfl_xor(s, off, 64);
    if (lane == 0) rowloss[row] = __logf(s) - tlogit[row];
}

__global__ void final_reduce(const float* __restrict__ rowloss, float* __restrict__ out) {
    __shared__ float red[256];
    int tid = threadIdx.x;
    float s = 0.f;
    for (int i = tid; i < NROWS; i += 256) s += rowloss[i];
    red[tid] = s;
    __syncthreads();
    for (int off = 128; off > 0; off >>= 1) {
        if (tid < off) red[tid] += red[tid + off];
        __syncthreads();
    }
    if (tid == 0) out[0] = red[0] * (1.0f / NROWS);
}

extern "C" void kernel_launch(void* const* d_in, const int* in_sizes, int n_in,
                              void* d_out, int out_size, void* d_ws, size_t ws_size,
                              hipStream_t stream) {
    const float*     features = (const float*)d_in[0];
    const long long* target   = (const long long*)d_in[1];
    const float*     weight   = (const float*)d_in[2];
    const float*     bias     = (const float*)d_in[3];
    float* out = (float*)d_out;

    const size_t sz_fbf  = (size_t)NROWS * DDIM * 2;        // 4 MB
    const size_t sz_wbf  = (size_t)NCLS * DDIM * 2;         // 262 MB
    const size_t sz_part = (size_t)NROWS * CTILES * 4;      // 8 MB
    const size_t sz_row  = (size_t)NROWS * 4;

    char* ws = (char*)d_ws;
    size_t need_full = sz_fbf + sz_wbf + sz_part + 2 * sz_row;

    if (ws_size >= need_full) {
        size_t off = 0;
        unsigned short* fbf = (unsigned short*)(ws + off); off += sz_fbf;
        unsigned short* wbf = (unsigned short*)(ws + off); off += sz_wbf;
        float* partials     = (float*)(ws + off);          off += sz_part;
        float* tlogit       = (float*)(ws + off);          off += sz_row;
        float* rowloss      = (float*)(ws + off);          off += sz_row;

        hipLaunchKernelGGL(convert_swz, dim3(1024), dim3(256), 0, stream,
                           features, fbf, (long long)NROWS * (DDIM / 8));
        hipLaunchKernelGGL(convert_swz, dim3(2048), dim3(256), 0, stream,
                           weight, wbf, (long long)NCLS * (DDIM / 8));
        hipLaunchKernelGGL(gemm_bf16, dim3(RTILES * CTILES), dim3(256), 0, stream,
                           fbf, wbf, bias, target, partials, tlogit);
        hipLaunchKernelGGL(row_reduce, dim3(NROWS / 4), dim3(256), 0, stream,
                           partials, tlogit, rowloss);
        hipLaunchKernelGGL(final_reduce, dim3(1), dim3(256), 0, stream,
                           rowloss, out);
    } else {
        size_t off = 0;
        unsigned short* fbf = (unsigned short*)(ws + off); off += sz_fbf;
        float* partials     = (float*)(ws + off);          off += sz_part;
        float* tlogit       = (float*)(ws + off);          off += sz_row;
        float* rowloss      = (float*)(ws + off);          off += sz_row;

        hipLaunchKernelGGL(convert_swz, dim3(1024), dim3(256), 0, stream,
                           features, fbf, (long long)NROWS * (DDIM / 8));
        hipLaunchKernelGGL(gemm_f32w, dim3(RTILES * CTILES), dim3(256), 0, stream,
                           fbf, weight, bias, target, partials, tlogit);
        hipLaunchKernelGGL(row_reduce, dim3(NROWS / 4), dim3(256), 0, stream,
                           partials, tlogit, rowloss);
        hipLaunchKernelGGL(final_reduce, dim3(1), dim3(256), 0, stream,
                           rowloss, out);
    }
}

// Round 3
// 782.799 us; speedup vs baseline: 1.4364x; 1.1496x over previous
//
#include <hip/hip_runtime.h>
#include <cstdint>

#define NROWS 2048
#define DDIM  1024
#define NCLS  128000
#define BM 256
#define BN 256
#define BK 64
#define RTILES (NROWS / BM)   // 8
#define CTILES (NCLS / BN)    // 500
#define KTILES (DDIM / BK)    // 16

typedef __attribute__((ext_vector_type(8))) short bf16x8;
typedef __attribute__((ext_vector_type(4))) float f32x4;

__device__ __forceinline__ unsigned short f2bf(float x) {
    unsigned int u = __float_as_uint(x);
    u += 0x7fffu + ((u >> 16) & 1u);   // RNE
    return (unsigned short)(u >> 16);
}

__device__ __forceinline__ uint4 pack8(float4 a, float4 b) {
    uint4 r;
    r.x = (unsigned)f2bf(a.x) | ((unsigned)f2bf(a.y) << 16);
    r.y = (unsigned)f2bf(a.z) | ((unsigned)f2bf(a.w) << 16);
    r.z = (unsigned)f2bf(b.x) | ((unsigned)f2bf(b.y) << 16);
    r.w = (unsigned)f2bf(b.z) | ((unsigned)f2bf(b.w) << 16);
    return r;
}

__device__ __forceinline__ void async_load16(unsigned short* lds, const unsigned short* g) {
    __builtin_amdgcn_global_load_lds(
        (const __attribute__((address_space(1))) unsigned int*)(uintptr_t)g,
        (__attribute__((address_space(3))) unsigned int*)(uintptr_t)lds,
        16, 0, 0);
}

// plain row-major f32 -> bf16 (swizzle now lives in the GEMM stage addressing)
__global__ void convert_bf16(const float* __restrict__ src,
                             unsigned short* __restrict__ dst, long long n8) {
    for (long long idx = blockIdx.x * 256LL + threadIdx.x; idx < n8;
         idx += (long long)gridDim.x * 256) {
        const float* p = src + idx * 8;
        float4 v0 = *(const float4*)p;
        float4 v1 = *(const float4*)(p + 4);
        *(uint4*)(dst + idx * 8) = pack8(v0, v1);
    }
}

// ---- 16 MFMA of one C-quadrant (static reg indices per rule #20) ----------
template<int MH, int NH>
__device__ __forceinline__ void quad(f32x4 (&acc)[8][4], bf16x8 (&ar)[4][2], bf16x8 (&br)[4][2]) {
    __builtin_amdgcn_s_setprio(1);
#pragma unroll
    for (int ks = 0; ks < 2; ++ks)
#pragma unroll
        for (int mi = 0; mi < 4; ++mi)
#pragma unroll
            for (int nj = 0; nj < 2; ++nj)
                acc[MH*4+mi][NH*2+nj] = __builtin_amdgcn_mfma_f32_16x16x32_bf16(
                    ar[mi][ks], br[NH*2+nj][ks], acc[MH*4+mi][NH*2+nj], 0, 0, 0);
    __builtin_amdgcn_s_setprio(0);
}

__device__ __forceinline__ void loadAhalf(bf16x8 (&ar)[4][2], const unsigned short* buf,
                                          int arow, int xo0, int xo1, int mh) {
#pragma unroll
    for (int mi = 0; mi < 4; ++mi) {
        ar[mi][0] = *(const bf16x8*)&buf[arow + (mh*4+mi)*1024 + xo0];
        ar[mi][1] = *(const bf16x8*)&buf[arow + (mh*4+mi)*1024 + xo1];
    }
}

template<int NH>
__device__ __forceinline__ void loadBpair(bf16x8 (&br)[4][2], const unsigned short* buf,
                                          int brl, int xo0, int xo1) {
#pragma unroll
    for (int nj = 0; nj < 2; ++nj) {
        br[NH*2+nj][0] = *(const bf16x8*)&buf[brl + (NH*2+nj)*1024 + xo0];
        br[NH*2+nj][1] = *(const bf16x8*)&buf[brl + (NH*2+nj)*1024 + xo1];
    }
}

#define BAR() do { __builtin_amdgcn_sched_barrier(0); __builtin_amdgcn_s_barrier(); \
                   __builtin_amdgcn_sched_barrier(0); } while (0)
#define VMCNT2() asm volatile("s_waitcnt vmcnt(2)" ::: "memory")

__global__ __launch_bounds__(512, 2) void gemm8(
    const unsigned short* __restrict__ A,   // [NROWS][DDIM] bf16 row-major
    const unsigned short* __restrict__ B,   // [NCLS][DDIM] bf16 row-major
    const float* __restrict__ bias,
    const long long* __restrict__ target,
    float* __restrict__ partials,           // [NROWS][CTILES]
    float* __restrict__ tlogit)             // [NROWS]
{
    __shared__ __align__(16) unsigned short Abuf[2][BM * BK];  // 2 x 32 KiB
    __shared__ __align__(16) unsigned short Bbuf[2][BN * BK];  // 2 x 32 KiB

    // XCD-bijective swizzle (4000 % 8 == 0); row-tiles consecutive per XCD.
    const int cpx = (RTILES * CTILES) / 8;   // 500
    int wg  = blockIdx.x;
    int swz = (wg & 7) * cpx + (wg >> 3);
    const int rt = swz & (RTILES - 1);
    const int ct = swz >> 3;
    const int brow = rt * BM;
    const int bcol = ct * BN;

    const int tid  = threadIdx.x;
    const int lane = tid & 63;
    const int wid  = tid >> 6;   // 0..7
    const int wr = wid >> 2;     // 0..1  (M half)
    const int wc = wid & 3;      // 0..3  (N quarter)

    // ---- staging: linear LDS dest, XOR-swizzled global source (rule #21)
    const int lrow = lane >> 3;                       // 0..7
    const int c8   = ((lane & 7) ^ lrow) * 8;         // logical 16B-chunk offset (bf16 units)
    const unsigned short* Asrc = A + (size_t)(brow + wid * 16 + lrow) * DDIM + c8;
    const unsigned short* Bsrc = B + (size_t)(bcol + wid * 16 + lrow) * DDIM + c8;
    const int dstb = wid * 1024;                      // ushort units within 16KiB half

#define STAGEA(kt, h, bi) do { \
    const unsigned short* _s = Asrc + (size_t)((h) * 128) * DDIM + (kt) * BK; \
    async_load16(&Abuf[bi][(h) * 8192 + dstb],       _s); \
    async_load16(&Abuf[bi][(h) * 8192 + dstb + 512], _s + 8 * DDIM); } while (0)
#define STAGEB(kt, h, bi) do { \
    const unsigned short* _s = Bsrc + (size_t)((h) * 128) * DDIM + (kt) * BK; \
    async_load16(&Bbuf[bi][(h) * 8192 + dstb],       _s); \
    async_load16(&Bbuf[bi][(h) * 8192 + dstb + 512], _s + 8 * DDIM); } while (0)

    // ---- fragment read addressing (undo swizzle at read)
    const int fr = lane & 15;
    const int gk = lane >> 4;
    const int xo0 = ((0 * 4 + gk) ^ (fr & 7)) * 8;    // ks=0
    const int xo1 = ((1 * 4 + gk) ^ (fr & 7)) * 8;    // ks=1
    const int arow = (wr * 128 + fr) * 64;            // ushort units (row stride 128B)
    const int brl  = (wc * 64 + fr) * 64;

    f32x4 acc[8][4] = {};
    bf16x8 ar[4][2], br[4][2];

    // ---- prologue: tile0 (all 4 halves -> buf0) + tile1 A-h0 -> buf1
    STAGEA(0, 0, 0); STAGEA(0, 1, 0);
    STAGEB(0, 0, 0); STAGEB(0, 1, 0);
    STAGEA(1, 0, 1);
    VMCNT2();
    BAR();

    for (int i = 0; i < KTILES / 2; ++i) {
        const int t1 = 2 * i + 1;
        const int t2 = (2 * i + 2 < KTILES) ? 2 * i + 2 : KTILES - 1;  // clamp: benign restage
        const int t3 = (2 * i + 3 < KTILES) ? 2 * i + 3 : KTILES - 1;

        // phase 1: compute tile 2i (buf0) quadrant (0,0)
        loadAhalf(ar, Abuf[0], arow, xo0, xo1, 0);
        loadBpair<0>(br, Bbuf[0], brl, xo0, xo1);
        STAGEA(t1, 1, 1);
        BAR();
        quad<0, 0>(acc, ar, br);
        BAR();
        // phase 2: quadrant (0,1)
        loadBpair<1>(br, Bbuf[0], brl, xo0, xo1);
        STAGEB(t1, 0, 1);
        BAR();
        quad<0, 1>(acc, ar, br);
        BAR();
        // phase 3: quadrant (1,1)
        loadAhalf(ar, Abuf[0], arow, xo0, xo1, 1);
        STAGEB(t1, 1, 1);
        BAR();
        quad<1, 1>(acc, ar, br);
        BAR();
        // phase 4: quadrant (1,0) (regs only); counted wait for tile 2i+1
        STAGEA(t2, 0, 0);
        VMCNT2();
        BAR();
        quad<1, 0>(acc, ar, br);
        BAR();
        // phase 5: compute tile 2i+1 (buf1) quadrant (0,0)
        loadAhalf(ar, Abuf[1], arow, xo0, xo1, 0);
        loadBpair<0>(br, Bbuf[1], brl, xo0, xo1);
        STAGEA(t2, 1, 0);
        BAR();
        quad<0, 0>(acc, ar, br);
        BAR();
        // phase 6: quadrant (0,1)
        loadBpair<1>(br, Bbuf[1], brl, xo0, xo1);
        STAGEB(t2, 0, 0);
        BAR();
        quad<0, 1>(acc, ar, br);
        BAR();
        // phase 7: quadrant (1,1)
        loadAhalf(ar, Abuf[1], arow, xo0, xo1, 1);
        STAGEB(t2, 1, 0);
        BAR();
        quad<1, 1>(acc, ar, br);
        BAR();
        // phase 8: quadrant (1,0); counted wait for tile 2i+2
        STAGEA(t3, 0, 1);
        VMCNT2();
        BAR();
        quad<1, 0>(acc, ar, br);
        BAR();
    }
#undef STAGEA
#undef STAGEB

    // ---- epilogue: drain pipeline (vmcnt(0)+lgkmcnt(0)+barrier), reuse LDS
    __syncthreads();
    float* rowsum = (float*)&Abuf[0][0];   // [256][4]

    float bval[4];
    int   cls[4];
#pragma unroll
    for (int n = 0; n < 4; ++n) {
        cls[n]  = bcol + wc * 64 + n * 16 + fr;
        bval[n] = bias[cls[n]];
    }
#pragma unroll
    for (int m = 0; m < 8; ++m) {
#pragma unroll
        for (int j = 0; j < 4; ++j) {
            const int rl = wr * 128 + m * 16 + gk * 4 + j;   // C/D: row=(lane>>4)*4+j, col=fr
            long long tgt = target[brow + rl];
            float s = 0.f;
#pragma unroll
            for (int n = 0; n < 4; ++n) {
                float lg = acc[m][n][j] + bval[n];
                if (tgt == (long long)cls[n]) tlogit[brow + rl] = lg;
                s += __expf(lg);
            }
#pragma unroll
            for (int off = 1; off < 16; off <<= 1) s += __shfl_xor(s, off, 64);
            if (fr == 0) rowsum[rl * 4 + wc] = s;
        }
    }
    __syncthreads();
    if (tid < 256) {
        float v = rowsum[tid * 4 + 0] + rowsum[tid * 4 + 1]
                + rowsum[tid * 4 + 2] + rowsum[tid * 4 + 3];
        partials[(size_t)(brow + tid) * CTILES + ct] = v;
    }
}

__global__ void row_reduce(const float* __restrict__ partials,
                           const float* __restrict__ tlogit,
                           float* __restrict__ rowloss) {
    int lane = threadIdx.x & 63;
    int wid  = threadIdx.x >> 6;
    int row  = blockIdx.x * 4 + wid;
    const float* p = partials + (size_t)row * CTILES;
    float s = 0.f;
    for (int i = lane; i < CTILES; i += 64) s += p[i];
#pragma unroll
    for (int off = 1; off < 64; off <<= 1) s += __shfl_xor(s, off, 64);
    if (lane == 0) rowloss[row] = __logf(s) - tlogit[row];
}

__global__ void final_reduce(const float* __restrict__ rowloss, float* __restrict__ out) {
    __shared__ float red[256];
    int tid = threadIdx.x;
    float s = 0.f;
    for (int i = tid; i < NROWS; i += 256) s += rowloss[i];
    red[tid] = s;
    __syncthreads();
    for (int off = 128; off > 0; off >>= 1) {
        if (tid < off) red[tid] += red[tid + off];
        __syncthreads();
    }
    if (tid == 0) out[0] = red[0] * (1.0f / NROWS);
}

extern "C" void kernel_launch(void* const* d_in, const int* in_sizes, int n_in,
                              void* d_out, int out_size, void* d_ws, size_t ws_size,
                              hipStream_t stream) {
    const float*     features = (const float*)d_in[0];
    const long long* target   = (const long long*)d_in[1];
    const float*     weight   = (const float*)d_in[2];
    const float*     bias     = (const float*)d_in[3];
    float* out = (float*)d_out;

    char* ws = (char*)d_ws;
    size_t off = 0;
    unsigned short* fbf = (unsigned short*)(ws + off); off += (size_t)NROWS * DDIM * 2;   // 4 MB
    unsigned short* wbf = (unsigned short*)(ws + off); off += (size_t)NCLS * DDIM * 2;    // 262 MB
    float* partials     = (float*)(ws + off);          off += (size_t)NROWS * CTILES * 4; // 4 MB
    float* tlogit       = (float*)(ws + off);          off += (size_t)NROWS * 4;
    float* rowloss      = (float*)(ws + off);          off += (size_t)NROWS * 4;

    hipLaunchKernelGGL(convert_bf16, dim3(1024), dim3(256), 0, stream,
                       features, fbf, (long long)NROWS * (DDIM / 8));
    hipLaunchKernelGGL(convert_bf16, dim3(4096), dim3(256), 0, stream,
                       weight, wbf, (long long)NCLS * (DDIM / 8));
    hipLaunchKernelGGL(gemm8, dim3(RTILES * CTILES), dim3(512), 0, stream,
                       fbf, wbf, bias, target, partials, tlogit);
    hipLaunchKernelGGL(row_reduce, dim3(NROWS / 4), dim3(256), 0, stream,
                       partials, tlogit, rowloss);
    hipLaunchKernelGGL(final_reduce, dim3(1), dim3(256), 0, stream,
                       rowloss, out);
}

// Round 4
// 759.077 us; speedup vs baseline: 1.4812x; 1.0313x over previous
//
#include <hip/hip_runtime.h>
#include <cstdint>

#define NROWS 2048
#define DDIM  1024
#define NCLS  128000
#define BM 256
#define BN 256
#define BK 64
#define RTILES (NROWS / BM)   // 8
#define CTILES (NCLS / BN)    // 500
#define KTILES (DDIM / BK)    // 16

typedef __attribute__((ext_vector_type(8))) short bf16x8;
typedef __attribute__((ext_vector_type(4))) float f32x4;

__device__ __forceinline__ unsigned short f2bf(float x) {
    unsigned int u = __float_as_uint(x);
    u += 0x7fffu + ((u >> 16) & 1u);   // RNE
    return (unsigned short)(u >> 16);
}

__device__ __forceinline__ uint4 pack8(float4 a, float4 b) {
    uint4 r;
    r.x = (unsigned)f2bf(a.x) | ((unsigned)f2bf(a.y) << 16);
    r.y = (unsigned)f2bf(a.z) | ((unsigned)f2bf(a.w) << 16);
    r.z = (unsigned)f2bf(b.x) | ((unsigned)f2bf(b.y) << 16);
    r.w = (unsigned)f2bf(b.z) | ((unsigned)f2bf(b.w) << 16);
    return r;
}

__device__ __forceinline__ void async_load16(unsigned short* lds, const unsigned short* g) {
    __builtin_amdgcn_global_load_lds(
        (const __attribute__((address_space(1))) unsigned int*)(uintptr_t)g,
        (__attribute__((address_space(3))) unsigned int*)(uintptr_t)lds,
        16, 0, 0);
}

// plain row-major f32 -> bf16
__global__ void convert_bf16(const float* __restrict__ src,
                             unsigned short* __restrict__ dst, long long n8) {
    for (long long idx = blockIdx.x * 256LL + threadIdx.x; idx < n8;
         idx += (long long)gridDim.x * 256) {
        const float* p = src + idx * 8;
        float4 v0 = *(const float4*)p;
        float4 v1 = *(const float4*)(p + 4);
        *(uint4*)(dst + idx * 8) = pack8(v0, v1);
    }
}

// ---- 16 MFMA of one C-quadrant (static reg indices per rule #20) ----------
template<int MH, int NH>
__device__ __forceinline__ void quad(f32x4 (&acc)[8][4], bf16x8 (&ar)[4][2], bf16x8 (&br)[4][2]) {
    __builtin_amdgcn_s_setprio(1);
#pragma unroll
    for (int ks = 0; ks < 2; ++ks)
#pragma unroll
        for (int mi = 0; mi < 4; ++mi)
#pragma unroll
            for (int nj = 0; nj < 2; ++nj)
                acc[MH*4+mi][NH*2+nj] = __builtin_amdgcn_mfma_f32_16x16x32_bf16(
                    ar[mi][ks], br[NH*2+nj][ks], acc[MH*4+mi][NH*2+nj], 0, 0, 0);
    __builtin_amdgcn_s_setprio(0);
}

__device__ __forceinline__ void loadAhalf(bf16x8 (&ar)[4][2], const unsigned short* buf,
                                          int arow, int xo0, int xo1, int mh) {
#pragma unroll
    for (int mi = 0; mi < 4; ++mi) {
        ar[mi][0] = *(const bf16x8*)&buf[arow + (mh*4+mi)*1024 + xo0];
        ar[mi][1] = *(const bf16x8*)&buf[arow + (mh*4+mi)*1024 + xo1];
    }
}

template<int NH>
__device__ __forceinline__ void loadBpair(bf16x8 (&br)[4][2], const unsigned short* buf,
                                          int brl, int xo0, int xo1) {
#pragma unroll
    for (int nj = 0; nj < 2; ++nj) {
        br[NH*2+nj][0] = *(const bf16x8*)&buf[brl + (NH*2+nj)*1024 + xo0];
        br[NH*2+nj][1] = *(const bf16x8*)&buf[brl + (NH*2+nj)*1024 + xo1];
    }
}

#define BAR() do { __builtin_amdgcn_sched_barrier(0); __builtin_amdgcn_s_barrier(); \
                   __builtin_amdgcn_sched_barrier(0); } while (0)
#define VMCNT0() asm volatile("s_waitcnt vmcnt(0)" ::: "memory")

__global__ __launch_bounds__(512, 2) void gemm8(
    const unsigned short* __restrict__ A,   // [NROWS][DDIM] bf16 row-major
    const unsigned short* __restrict__ B,   // [NCLS][DDIM] bf16 row-major
    const float* __restrict__ bias,
    const long long* __restrict__ target,
    float* __restrict__ partials,           // [NROWS][CTILES]
    float* __restrict__ tlogit)             // [NROWS]
{
    __shared__ __align__(16) unsigned short Abuf[2][BM * BK];  // 2 x 32 KiB
    __shared__ __align__(16) unsigned short Bbuf[2][BN * BK];  // 2 x 32 KiB

    // XCD-bijective swizzle (4000 % 8 == 0); row-tiles consecutive per XCD.
    const int cpx = (RTILES * CTILES) / 8;   // 500
    int wg  = blockIdx.x;
    int swz = (wg & 7) * cpx + (wg >> 3);
    const int rt = swz & (RTILES - 1);
    const int ct = swz >> 3;
    const int brow = rt * BM;
    const int bcol = ct * BN;

    const int tid  = threadIdx.x;
    const int lane = tid & 63;
    const int wid  = tid >> 6;   // 0..7
    const int wr = wid >> 2;     // 0..1  (M half)
    const int wc = wid & 3;      // 0..3  (N quarter)

    // ---- staging: linear LDS dest, XOR-swizzled global source (rule #21)
    const int lrow = lane >> 3;                       // 0..7
    const int c8   = ((lane & 7) ^ lrow) * 8;         // swizzled 16B-chunk (bf16 units)
    const unsigned short* Asrc = A + (size_t)(brow + wid * 16 + lrow) * DDIM + c8;
    const unsigned short* Bsrc = B + (size_t)(bcol + wid * 16 + lrow) * DDIM + c8;
    const int dstb = wid * 1024;                      // ushort units within 16KiB half

#define STAGEA(kt, h, bi) do { \
    const unsigned short* _s = Asrc + (size_t)((h) * 128) * DDIM + (kt) * BK; \
    async_load16(&Abuf[bi][(h) * 8192 + dstb],       _s); \
    async_load16(&Abuf[bi][(h) * 8192 + dstb + 512], _s + 8 * DDIM); } while (0)
#define STAGEB(kt, h, bi) do { \
    const unsigned short* _s = Bsrc + (size_t)((h) * 128) * DDIM + (kt) * BK; \
    async_load16(&Bbuf[bi][(h) * 8192 + dstb],       _s); \
    async_load16(&Bbuf[bi][(h) * 8192 + dstb + 512], _s + 8 * DDIM); } while (0)

    // ---- fragment read addressing (undo swizzle at read)
    const int fr = lane & 15;
    const int gk = lane >> 4;
    const int xo0 = ((0 * 4 + gk) ^ (fr & 7)) * 8;    // ks=0
    const int xo1 = ((1 * 4 + gk) ^ (fr & 7)) * 8;    // ks=1
    const int arow = (wr * 128 + fr) * 64;            // ushort units (row stride 128B)
    const int brl  = (wc * 64 + fr) * 64;

    f32x4 acc[8][4] = {};
    bf16x8 ar[4][2], br[4][2];

    // ---- prologue: tile 0 -> buf0, exact drain
    STAGEB(0, 1, 0); STAGEB(0, 0, 0);
    STAGEA(0, 1, 0); STAGEA(0, 0, 0);
    VMCNT0();
    BAR();

    // ---- window: compute tile T (buf PAR), stage tile kt=T+1 (buf PAR^1)
    // Stages front-loaded into phases 1-2 (B first: L3/HBM-cold; A is L2-hot)
    // -> issue-to-wait distance 2-3 phases. Single exact vmcnt(0) at phase 4
    // (only this window's 8 stage-loads outstanding there).
#define WINDOW(PAR, DOSTAGE, kt) do { \
    /* P1 */ \
    loadAhalf(ar, Abuf[PAR], arow, xo0, xo1, 0); \
    loadBpair<0>(br, Bbuf[PAR], brl, xo0, xo1); \
    if (DOSTAGE) { STAGEB(kt, 1, (PAR)^1); STAGEB(kt, 0, (PAR)^1); } \
    BAR(); quad<0, 0>(acc, ar, br); BAR(); \
    /* P2 */ \
    loadBpair<1>(br, Bbuf[PAR], brl, xo0, xo1); \
    if (DOSTAGE) { STAGEA(kt, 1, (PAR)^1); STAGEA(kt, 0, (PAR)^1); } \
    BAR(); quad<0, 1>(acc, ar, br); BAR(); \
    /* P3 */ \
    loadAhalf(ar, Abuf[PAR], arow, xo0, xo1, 1); \
    BAR(); quad<1, 1>(acc, ar, br); BAR(); \
    /* P4 */ \
    if (DOSTAGE) { VMCNT0(); } \
    BAR(); quad<1, 0>(acc, ar, br); BAR(); \
} while (0)

    for (int i = 0; i < (KTILES - 2) / 2; ++i) {   // T = 0..13
        WINDOW(0, true, 2 * i + 1);
        WINDOW(1, true, 2 * i + 2);
    }
    WINDOW(0, true, KTILES - 1);   // T = 14, stages tile 15
    WINDOW(1, false, 0);           // T = 15, no stage

#undef WINDOW
#undef STAGEA
#undef STAGEB

    // ---- epilogue: drain + LDS reuse
    __syncthreads();
    float* rowsum = (float*)&Abuf[0][0];   // [256][4]

    float bval[4];
    int   cls[4];
#pragma unroll
    for (int n = 0; n < 4; ++n) {
        cls[n]  = bcol + wc * 64 + n * 16 + fr;
        bval[n] = bias[cls[n]];
    }
#pragma unroll
    for (int m = 0; m < 8; ++m) {
#pragma unroll
        for (int j = 0; j < 4; ++j) {
            const int rl = wr * 128 + m * 16 + gk * 4 + j;   // C/D: row=(lane>>4)*4+j, col=fr
            long long tgt = target[brow + rl];
            float s = 0.f;
#pragma unroll
            for (int n = 0; n < 4; ++n) {
                float lg = acc[m][n][j] + bval[n];
                if (tgt == (long long)cls[n]) tlogit[brow + rl] = lg;
                s += __expf(lg);
            }
#pragma unroll
            for (int off = 1; off < 16; off <<= 1) s += __shfl_xor(s, off, 64);
            if (fr == 0) rowsum[rl * 4 + wc] = s;
        }
    }
    __syncthreads();
    if (tid < 256) {
        float v = rowsum[tid * 4 + 0] + rowsum[tid * 4 + 1]
                + rowsum[tid * 4 + 2] + rowsum[tid * 4 + 3];
        partials[(size_t)(brow + tid) * CTILES + ct] = v;
    }
}

__global__ void row_reduce(const float* __restrict__ partials,
                           const float* __restrict__ tlogit,
                           float* __restrict__ rowloss) {
    int lane = threadIdx.x & 63;
    int wid  = threadIdx.x >> 6;
    int row  = blockIdx.x * 4 + wid;
    const float* p = partials + (size_t)row * CTILES;
    float s = 0.f;
    for (int i = lane; i < CTILES; i += 64) s += p[i];
#pragma unroll
    for (int off = 1; off < 64; off <<= 1) s += __shfl_xor(s, off, 64);
    if (lane == 0) rowloss[row] = __logf(s) - tlogit[row];
}

__global__ void final_reduce(const float* __restrict__ rowloss, float* __restrict__ out) {
    __shared__ float red[256];
    int tid = threadIdx.x;
    float s = 0.f;
    for (int i = tid; i < NROWS; i += 256) s += rowloss[i];
    red[tid] = s;
    __syncthreads();
    for (int off = 128; off > 0; off >>= 1) {
        if (tid < off) red[tid] += red[tid + off];
        __syncthreads();
    }
    if (tid == 0) out[0] = red[0] * (1.0f / NROWS);
}

extern "C" void kernel_launch(void* const* d_in, const int* in_sizes, int n_in,
                              void* d_out, int out_size, void* d_ws, size_t ws_size,
                              hipStream_t stream) {
    const float*     features = (const float*)d_in[0];
    const long long* target   = (const long long*)d_in[1];
    const float*     weight   = (const float*)d_in[2];
    const float*     bias     = (const float*)d_in[3];
    float* out = (float*)d_out;

    char* ws = (char*)d_ws;
    size_t off = 0;
    unsigned short* fbf = (unsigned short*)(ws + off); off += (size_t)NROWS * DDIM * 2;   // 4 MB
    unsigned short* wbf = (unsigned short*)(ws + off); off += (size_t)NCLS * DDIM * 2;    // 262 MB
    float* partials     = (float*)(ws + off);          off += (size_t)NROWS * CTILES * 4; // 4 MB
    float* tlogit       = (float*)(ws + off);          off += (size_t)NROWS * 4;
    float* rowloss      = (float*)(ws + off);          off += (size_t)NROWS * 4;

    hipLaunchKernelGGL(convert_bf16, dim3(1024), dim3(256), 0, stream,
                       features, fbf, (long long)NROWS * (DDIM / 8));
    hipLaunchKernelGGL(convert_bf16, dim3(4096), dim3(256), 0, stream,
                       weight, wbf, (long long)NCLS * (DDIM / 8));
    hipLaunchKernelGGL(gemm8, dim3(RTILES * CTILES), dim3(512), 0, stream,
                       fbf, wbf, bias, target, partials, tlogit);
    hipLaunchKernelGGL(row_reduce, dim3(NROWS / 4), dim3(256), 0, stream,
                       partials, tlogit, rowloss);
    hipLaunchKernelGGL(final_reduce, dim3(1), dim3(256), 0, stream,
                       rowloss, out);
}